// Round 18
// baseline (333.299 us; speedup 1.0000x reference)
//
#include <hip/hip_runtime.h>

// Capsule routing, B=64 R=2048 C=32 O=32 I=16, 3 routing iters.
// u_hat never materialized; recomputed per pass. Logit telescoping:
// b1 = u.v1 ; b2 = u.(v1+v2).
//
// R29 = R28 resubmit (R28 bench was GPUAcquisitionTimeout; no data).
// R28: OCCUPANCY x2 via RCH 16->8 (512 blocks = 2/CU), constant W traffic.
//   R25 counters (first upass visibility): VGPR=56(+64 AGPR), Mfma 3.8%,
//   VALU 2.7%, hbm 29%, Occupancy 16.6%. Per-CU rate 21 GB/s = exactly one
//   8KB wave-batch per ~375ns latency => memory-level-parallelism starved,
//   1 block/CU. Fix: split rc chunks (RCH=8, NRC2=256, 512 blocks = 2
//   blocks/CU). bound=2 (cap 128) so 16 waves x ~120 regs fit 2048/CU;
//   R15 measured bound=2 neutral with these bodies => cap is safe.
//   s_part grows 32->64MB (ws >= 512MB per the harness's 512MB fills).
//   W traffic UNCHANGED (unlike NG-split). Phase bodies identical to R25.
// R25 (kept): wconv folded into upass<0> (fp32 W read, in-reg cvt, bg==0
//   persists fp16 Wh); deleted the 30us wconv dispatch.
// R15 (kept): NG=2 b-fusion, 32 b/block; fused reduce_squash.
// R12 (kept): v in VGPRs; raw s_barrier + lgkmcnt-only drain.
// R11 baseline: MFMA 16x16x16 per tile; D row=4q+reg, col=lane&15.

#define Bn 64
#define Rn 2048
#define Cn 32
#define On 32
#define In 16
#define RCH 8             // r per block (R28: was 16)
#define NRC2 (Rn / RCH)   // 256 r-chunks
#define NG 2              // fused b-groups of 32

typedef _Float16 half4v __attribute__((ext_vector_type(4)));
typedef float floatx4 __attribute__((ext_vector_type(4)));

// s_part: [NRC2][64 b][1024 co] f32 (64 MB)
// PHASE 0: Wfp = W fp32 (reads + converts + persists fp16 to Wh).
// PHASE 1/2: Wh fp16 read path.
template <int PHASE>
__global__ __launch_bounds__(512, 2)
void upass(const float* __restrict__ x, const float* __restrict__ Wfp,
           _Float16* __restrict__ Wh, const float* __restrict__ vroute,
           float* __restrict__ s_part) {
    const int tid  = threadIdx.x;
    const int w    = tid >> 6;      // wave 0..7 -> c = 4w..4w+3
    const int lane = tid & 63;
    const int q    = lane >> 4;     // quad
    const int bl   = lane & 15;     // A row / B col / D col

    // XCD swizzle: the 2 bg-blocks of one rc are L and L+8 -> same XCD.
    const int L  = blockIdx.x;                  // [0,512)
    const int bg = (L >> 3) & 1;
    const int rc = (L & 7) | ((L >> 4) << 3);   // [0,256)
    const int b0 = bg * 32;

    // xs[rr][bb 32][20] halfs (pad 16->20: 8B-aligned b64, conflict-free)
    __shared__ __attribute__((aligned(16))) _Float16 xs[RCH * 32 * 20];
    __shared__ __attribute__((aligned(16))) float sums[2][2][16][8];

    // ---- v slice -> registers (r-invariant). g=0: b0+bl, g=1: b0+16+bl ----
    floatx4 v00[4], v01[4], v10[4], v11[4];
    if constexpr (PHASE > 0) {
        const float* vb0 = vroute + (size_t)(b0 + bl) * 1024 + 4 * q;
        const float* vb1 = vroute + (size_t)(b0 + 16 + bl) * 1024 + 4 * q;
#pragma unroll
        for (int t = 0; t < 4; ++t) {
            const int co = (w * 4 + t) * 32;
            v00[t] = *(const floatx4*)(vb0 + co);
            v01[t] = *(const floatx4*)(vb0 + co + 16);
            v10[t] = *(const floatx4*)(vb1 + co);
            v11[t] = *(const floatx4*)(vb1 + co + 16);
        }
    }

    // ---- preload x chunk -> fp16 LDS: 8 r x 32 b x 16 i ----
#pragma unroll
    for (int k = 0; k < 2; ++k) {
        const int u  = tid + k * 512;           // [0,1024)
        const int rr = u >> 7, bb = (u >> 2) & 31, iq = u & 3;
        const float4 xv = *(const float4*)(x + (size_t)(b0 + bb) * (Rn * In) +
                                           (size_t)(rc * RCH + rr) * In + iq * 4);
        union { _Float16 h[4]; uint2 u2; } p;
        p.h[0] = (_Float16)xv.x; p.h[1] = (_Float16)xv.y;
        p.h[2] = (_Float16)xv.z; p.h[3] = (_Float16)xv.w;
        *(uint2*)(xs + (rr * 32 + bb) * 20 + iq * 4) = p.u2;
    }
    __syncthreads();

    floatx4 accS0[8], accS1[8];
#pragma unroll
    for (int m = 0; m < 8; ++m) {
        accS0[m] = (floatx4){0.f, 0.f, 0.f, 0.f};
        accS1[m] = (floatx4){0.f, 0.f, 0.f, 0.f};
    }

    // A base: W[r, co = w*128 + m*16 + bl, i = 4q..4q+3]; per-r stride 16384 elems
    const size_t abase = ((size_t)(rc * RCH) * 1024 + w * 128 + bl) * 16 + 4 * q;

    half4v a[8];
    half4v bf0, bf1;
    if constexpr (PHASE > 0) {
        const _Float16* Wp = Wh + abase;
#pragma unroll
        for (int m = 0; m < 8; ++m) a[m] = *(const half4v*)(Wp + m * 256);
        bf0 = *(const half4v*)(xs + bl * 20 + 4 * q);
        bf1 = *(const half4v*)(xs + (16 + bl) * 20 + 4 * q);
    }

    for (int rr = 0; rr < RCH; ++rr) {
        if constexpr (PHASE == 0) {
            // fp32 W read (1KB coalesced segments), in-reg cvt, fp16 persist.
            const size_t rb = abase + (size_t)rr * 16384;
            const float* Wf = Wfp + rb;
            half4v af[8];
#pragma unroll
            for (int m = 0; m < 8; ++m) {
                const float4 t4 = *(const float4*)(Wf + m * 256);
                af[m] = (half4v){(_Float16)t4.x, (_Float16)t4.y,
                                 (_Float16)t4.z, (_Float16)t4.w};
            }
            if (bg == 0) {
                _Float16* whp = Wh + rb;
#pragma unroll
                for (int m = 0; m < 8; ++m) *(half4v*)(whp + m * 256) = af[m];
            }
            const half4v b0v = *(const half4v*)(xs + (rr * 32 + bl) * 20 + 4 * q);
            const half4v b1v = *(const half4v*)(xs + (rr * 32 + 16 + bl) * 20 + 4 * q);
#pragma unroll
            for (int m = 0; m < 8; ++m) {
                accS0[m] = __builtin_amdgcn_mfma_f32_16x16x16f16(af[m], b0v, accS0[m], 0, 0, 0);
                accS1[m] = __builtin_amdgcn_mfma_f32_16x16x16f16(af[m], b1v, accS1[m], 0, 0, 0);
            }
        } else {
            const int rn = (rr + 1 < RCH) ? rr + 1 : rr;     // clamped prefetch idx
            const _Float16* Wn = Wh + abase + (size_t)rn * 16384;

            floatx4 D0[8], D1[8];
#pragma unroll
            for (int m = 0; m < 8; ++m) {
                D0[m] = __builtin_amdgcn_mfma_f32_16x16x16f16(
                            a[m], bf0, (floatx4){0.f, 0.f, 0.f, 0.f}, 0, 0, 0);
                D1[m] = __builtin_amdgcn_mfma_f32_16x16x16f16(
                            a[m], bf1, (floatx4){0.f, 0.f, 0.f, 0.f}, 0, 0, 0);
            }

            // issue rr+1 fragment loads NOW; in flight across the barrier.
            const half4v bn0 = *(const half4v*)(xs + (rn * 32 + bl) * 20 + 4 * q);
            const half4v bn1 = *(const half4v*)(xs + (rn * 32 + 16 + bl) * 20 + 4 * q);
#pragma unroll
            for (int m = 0; m < 8; ++m) a[m] = *(const half4v*)(Wn + m * 256);
            bf0 = bn0; bf1 = bn1;

            // logits l[b,c] = sum_o u*v ; tile 2t: o=4q+reg, 2t+1: o=16+4q+reg
            float e0[4], e1[4], se0 = 0.f, se1 = 0.f;
#pragma unroll
            for (int t = 0; t < 4; ++t) {
                float lp0 = D0[2*t].x * v00[t].x + D0[2*t].y * v00[t].y +
                            D0[2*t].z * v00[t].z + D0[2*t].w * v00[t].w +
                            D0[2*t+1].x * v01[t].x + D0[2*t+1].y * v01[t].y +
                            D0[2*t+1].z * v01[t].z + D0[2*t+1].w * v01[t].w;
                float lp1 = D1[2*t].x * v10[t].x + D1[2*t].y * v10[t].y +
                            D1[2*t].z * v10[t].z + D1[2*t].w * v10[t].w +
                            D1[2*t+1].x * v11[t].x + D1[2*t+1].y * v11[t].y +
                            D1[2*t+1].z * v11[t].z + D1[2*t+1].w * v11[t].w;
                lp0 += __shfl_xor(lp0, 16, 64);   // sum over quads (o coverage)
                lp0 += __shfl_xor(lp0, 32, 64);
                lp1 += __shfl_xor(lp1, 16, 64);
                lp1 += __shfl_xor(lp1, 32, 64);
                e0[t] = __expf(lp0); se0 += e0[t]; // no max-subtract (|l| small)
                e1[t] = __expf(lp1); se1 += e1[t];
            }
            if (lane < 32) sums[rr & 1][q][bl][w] = (q == 0) ? se0 : se1;
            // lgkmcnt-only drain: LDS write visible, W loads stay in flight.
            asm volatile("s_waitcnt lgkmcnt(0)" ::: "memory");
            __builtin_amdgcn_s_barrier();
            asm volatile("" ::: "memory");
            const floatx4 sa0 = *(const floatx4*)(&sums[rr & 1][0][bl][0]);
            const floatx4 sa1 = *(const floatx4*)(&sums[rr & 1][0][bl][4]);
            const floatx4 sb0 = *(const floatx4*)(&sums[rr & 1][1][bl][0]);
            const floatx4 sb1 = *(const floatx4*)(&sums[rr & 1][1][bl][4]);
            const float tot0 = sa0.x + sa0.y + sa0.z + sa0.w +
                               sa1.x + sa1.y + sa1.z + sa1.w;
            const float tot1 = sb0.x + sb0.y + sb0.z + sb0.w +
                               sb1.x + sb1.y + sb1.z + sb1.w;
            const float winv0 = __builtin_amdgcn_rcpf(tot0);
            const float winv1 = __builtin_amdgcn_rcpf(tot1);
#pragma unroll
            for (int t = 0; t < 4; ++t) {
                const float wt0 = e0[t] * winv0;
                const float wt1 = e1[t] * winv1;
                accS0[2*t]   += wt0 * D0[2*t];
                accS0[2*t+1] += wt0 * D0[2*t+1];
                accS1[2*t]   += wt1 * D1[2*t];
                accS1[2*t+1] += wt1 * D1[2*t+1];
            }
        }
    }

    // store: co = w*128 + m*16 + 4q + reg; g=0 rows b0+bl, g=1 rows b0+16+bl
    const size_t sb = (((size_t)rc * 64 + b0 + bl)) * 1024 + w * 128 + 4 * q;
#pragma unroll
    for (int m = 0; m < 8; ++m) {
        *(floatx4*)(s_part + sb + m * 16) = accS0[m];
        *(floatx4*)(s_part + sb + (size_t)16 * 1024 + m * 16) = accS1[m];
    }
}

// Fused reduce(256 rc-partials) + squash. Grid: 64 b x 8 co-octs = 512 blocks.
// Each block: 256 thr = 8 k-groups x 32 float4 covering a 128-co slice
// (= 4 full capsules c, so the o-norm is block-local).
__global__ __launch_bounds__(256)
void reduce_squash(const float* __restrict__ sp, float scale,
                   float* __restrict__ vout, const float* __restrict__ vprev,
                   float* __restrict__ vsum) {
    const int b = blockIdx.x >> 3, oct = blockIdx.x & 7;
    const int t = threadIdx.x;
    const int kg = t >> 5, ci = t & 31;
    const size_t base = (size_t)b * 1024 + (size_t)oct * 128 + (size_t)ci * 4;

    floatx4 acc0 = (floatx4){0.f, 0.f, 0.f, 0.f};
    floatx4 acc1 = (floatx4){0.f, 0.f, 0.f, 0.f};
#pragma unroll 8
    for (int k = kg * 32; k < kg * 32 + 32; k += 2) {
        acc0 += *(const floatx4*)(sp + (size_t)k * 65536 + base);
        acc1 += *(const floatx4*)(sp + (size_t)(k + 1) * 65536 + base);
    }
    const floatx4 acc = acc0 + acc1;

    __shared__ __attribute__((aligned(16))) float red[8][128];
    *(floatx4*)(&red[kg][ci * 4]) = acc;
    __syncthreads();

    if (t < 128) {                     // element f = t : c = oct*4 + (t>>5), o = t&31
        float s = 0.f;
#pragma unroll
        for (int g = 0; g < 8; ++g) s += red[g][t];
        s *= scale;
        float n2 = s * s;              // norm over o: lane bits 0..4
        n2 += __shfl_xor(n2, 1, 64);
        n2 += __shfl_xor(n2, 2, 64);
        n2 += __shfl_xor(n2, 4, 64);
        n2 += __shfl_xor(n2, 8, 64);
        n2 += __shfl_xor(n2, 16, 64);
        const float norm = sqrtf(n2);
        const float f = (n2 / (1.f + n2)) / (norm + 1e-8f);
        const float vv = s * f;
        const size_t o = (size_t)b * 1024 + (size_t)oct * 128 + t;
        if (vout) vout[o] = vv;
        if (vsum) vsum[o] = vv + vprev[o];
    }
}

extern "C" void kernel_launch(void* const* d_in, const int* in_sizes, int n_in,
                              void* d_out, int out_size, void* d_ws, size_t ws_size,
                              hipStream_t stream) {
    const float* x = (const float*)d_in[0];   // [64,2048,16]
    const float* W = (const float*)d_in[1];   // [2048,32,32,16]
    float* out = (float*)d_out;               // [64,32,32]

    char* ws = (char*)d_ws;                   // ws >= 512 MB (harness fills 512MB)
    _Float16* Wh  = (_Float16*)ws;                              // 64 MB
    float* s_part = (float*)(ws + (size_t)67108864);            // 64 MB
    float* v1     = (float*)(ws + (size_t)67108864 + 67108864);             // 256 KB
    float* v12    = (float*)(ws + (size_t)67108864 + 67108864 + 262144);    // 256 KB

    const int ublocks = NG * NRC2;   // 512 = 2 blocks/CU

    // iter 1: reads W fp32, persists Wh fp16; 1/32 applied as squash pre-scale
    upass<0><<<ublocks, 512, 0, stream>>>(x, W, Wh, nullptr, s_part);
    reduce_squash<<<512, 256, 0, stream>>>(s_part, 1.f / 32.f, v1, nullptr, nullptr);

    // iter 2: logits = u.v1 ; keep only v12 = v1 + v2
    upass<1><<<ublocks, 512, 0, stream>>>(x, nullptr, Wh, v1, s_part);
    reduce_squash<<<512, 256, 0, stream>>>(s_part, 1.f, nullptr, v1, v12);

    // iter 3: logits = u.(v1+v2) ; output v3
    upass<2><<<ublocks, 512, 0, stream>>>(x, nullptr, Wh, v12, s_part);
    reduce_squash<<<512, 256, 0, stream>>>(s_part, 1.f, out, nullptr, nullptr);
}

// Round 19
// 286.938 us; speedup vs baseline: 1.1616x; 1.1616x over previous
//
#include <hip/hip_runtime.h>

// Capsule routing, B=64 R=2048 C=32 O=32 I=16, 3 routing iters.
// u_hat never materialized; recomputed per pass. Logit telescoping:
// b1 = u.v1 ; b2 = u.(v1+v2).
//
// R30: REVERT R28 split + FP16 s_part (traffic cut at the BW wall).
//   R28 post-mortem: occupancy 16.6->32% as predicted but hbm_gbps only
//   +5% (2330->2450) and dur 82->90us (extra s_part traffic). Occupancy
//   lever REFUTED: kernel family saturates ~2.45 TB/s effective BW
//   regardless of waves/CU. Model: total traffic / 2.45 TB/s = wall time
//   (R25 ~640MB->~260us, R28 ~790MB->~320us — both match). Only lever:
//   LESS TRAFFIC. This round: (a) revert to RCH=16/256 blocks/bound=1
//   (R25 geometry, 293us); (b) s_part fp32->fp16 (32->16 MB): saves
//   96 MB total => ~-40us. Partials are 16-r sums; fp32 accumulation in
//   reduce_squash; error ~2.4e-4 on v, under the 2^-8 fp16-W floor.
// R25 (kept): wconv folded into upass<0> (fp32 W read, in-reg cvt, bg==0
//   persists fp16 Wh); no separate wconv dispatch.
// R15 (kept): NG=2 b-fusion, 32 b/block; fused reduce_squash.
// R12 (kept): v in VGPRs; raw s_barrier + lgkmcnt-only drain.
// R11 baseline: MFMA 16x16x16 per tile; D row=4q+reg, col=lane&15.

#define Bn 64
#define Rn 2048
#define Cn 32
#define On 32
#define In 16
#define RCH 16            // r per block (reverted)
#define NRC2 (Rn / RCH)   // 128 r-chunks
#define NG 2              // fused b-groups of 32

typedef _Float16 half4v __attribute__((ext_vector_type(4)));
typedef float floatx4 __attribute__((ext_vector_type(4)));

// s_part: [NRC2][64 b][1024 co] fp16 (16 MB)
// PHASE 0: Wfp = W fp32 (reads + converts + persists fp16 to Wh).
// PHASE 1/2: Wh fp16 read path.
template <int PHASE>
__global__ __launch_bounds__(512, 1)
void upass(const float* __restrict__ x, const float* __restrict__ Wfp,
           _Float16* __restrict__ Wh, const float* __restrict__ vroute,
           _Float16* __restrict__ s_part) {
    const int tid  = threadIdx.x;
    const int w    = tid >> 6;      // wave 0..7 -> c = 4w..4w+3
    const int lane = tid & 63;
    const int q    = lane >> 4;     // quad
    const int bl   = lane & 15;     // A row / B col / D col

    // XCD swizzle: the 2 bg-blocks of one rc are L and L+8 -> same XCD.
    const int L  = blockIdx.x;                  // [0,256)
    const int bg = (L >> 3) & 1;
    const int rc = (L & 7) | ((L >> 4) << 3);   // [0,128)
    const int b0 = bg * 32;

    // xs[rr][bb 32][20] halfs (pad 16->20: 8B-aligned b64, conflict-free)
    __shared__ __attribute__((aligned(16))) _Float16 xs[RCH * 32 * 20];
    __shared__ __attribute__((aligned(16))) float sums[2][2][16][8];

    // ---- v slice -> registers (r-invariant). g=0: b0+bl, g=1: b0+16+bl ----
    floatx4 v00[4], v01[4], v10[4], v11[4];
    if constexpr (PHASE > 0) {
        const float* vb0 = vroute + (size_t)(b0 + bl) * 1024 + 4 * q;
        const float* vb1 = vroute + (size_t)(b0 + 16 + bl) * 1024 + 4 * q;
#pragma unroll
        for (int t = 0; t < 4; ++t) {
            const int co = (w * 4 + t) * 32;
            v00[t] = *(const floatx4*)(vb0 + co);
            v01[t] = *(const floatx4*)(vb0 + co + 16);
            v10[t] = *(const floatx4*)(vb1 + co);
            v11[t] = *(const floatx4*)(vb1 + co + 16);
        }
    }

    // ---- preload x chunk -> fp16 LDS: 16 r x 32 b x 16 i ----
#pragma unroll
    for (int k = 0; k < 4; ++k) {
        const int u  = tid + k * 512;           // [0,2048)
        const int rr = u >> 7, bb = (u >> 2) & 31, iq = u & 3;
        const float4 xv = *(const float4*)(x + (size_t)(b0 + bb) * (Rn * In) +
                                           (size_t)(rc * RCH + rr) * In + iq * 4);
        union { _Float16 h[4]; uint2 u2; } p;
        p.h[0] = (_Float16)xv.x; p.h[1] = (_Float16)xv.y;
        p.h[2] = (_Float16)xv.z; p.h[3] = (_Float16)xv.w;
        *(uint2*)(xs + (rr * 32 + bb) * 20 + iq * 4) = p.u2;
    }
    __syncthreads();

    floatx4 accS0[8], accS1[8];
#pragma unroll
    for (int m = 0; m < 8; ++m) {
        accS0[m] = (floatx4){0.f, 0.f, 0.f, 0.f};
        accS1[m] = (floatx4){0.f, 0.f, 0.f, 0.f};
    }

    // A base: W[r, co = w*128 + m*16 + bl, i = 4q..4q+3]; per-r stride 16384 elems
    const size_t abase = ((size_t)(rc * RCH) * 1024 + w * 128 + bl) * 16 + 4 * q;

    half4v a[8];
    half4v bf0, bf1;
    if constexpr (PHASE > 0) {
        const _Float16* Wp = Wh + abase;
#pragma unroll
        for (int m = 0; m < 8; ++m) a[m] = *(const half4v*)(Wp + m * 256);
        bf0 = *(const half4v*)(xs + bl * 20 + 4 * q);
        bf1 = *(const half4v*)(xs + (16 + bl) * 20 + 4 * q);
    }

    for (int rr = 0; rr < RCH; ++rr) {
        if constexpr (PHASE == 0) {
            // fp32 W read (1KB coalesced segments), in-reg cvt, fp16 persist.
            const size_t rb = abase + (size_t)rr * 16384;
            const float* Wf = Wfp + rb;
            half4v af[8];
#pragma unroll
            for (int m = 0; m < 8; ++m) {
                const float4 t4 = *(const float4*)(Wf + m * 256);
                af[m] = (half4v){(_Float16)t4.x, (_Float16)t4.y,
                                 (_Float16)t4.z, (_Float16)t4.w};
            }
            if (bg == 0) {
                _Float16* whp = Wh + rb;
#pragma unroll
                for (int m = 0; m < 8; ++m) *(half4v*)(whp + m * 256) = af[m];
            }
            const half4v b0v = *(const half4v*)(xs + (rr * 32 + bl) * 20 + 4 * q);
            const half4v b1v = *(const half4v*)(xs + (rr * 32 + 16 + bl) * 20 + 4 * q);
#pragma unroll
            for (int m = 0; m < 8; ++m) {
                accS0[m] = __builtin_amdgcn_mfma_f32_16x16x16f16(af[m], b0v, accS0[m], 0, 0, 0);
                accS1[m] = __builtin_amdgcn_mfma_f32_16x16x16f16(af[m], b1v, accS1[m], 0, 0, 0);
            }
        } else {
            const int rn = (rr + 1 < RCH) ? rr + 1 : rr;     // clamped prefetch idx
            const _Float16* Wn = Wh + abase + (size_t)rn * 16384;

            floatx4 D0[8], D1[8];
#pragma unroll
            for (int m = 0; m < 8; ++m) {
                D0[m] = __builtin_amdgcn_mfma_f32_16x16x16f16(
                            a[m], bf0, (floatx4){0.f, 0.f, 0.f, 0.f}, 0, 0, 0);
                D1[m] = __builtin_amdgcn_mfma_f32_16x16x16f16(
                            a[m], bf1, (floatx4){0.f, 0.f, 0.f, 0.f}, 0, 0, 0);
            }

            // issue rr+1 fragment loads NOW; in flight across the barrier.
            const half4v bn0 = *(const half4v*)(xs + (rn * 32 + bl) * 20 + 4 * q);
            const half4v bn1 = *(const half4v*)(xs + (rn * 32 + 16 + bl) * 20 + 4 * q);
#pragma unroll
            for (int m = 0; m < 8; ++m) a[m] = *(const half4v*)(Wn + m * 256);
            bf0 = bn0; bf1 = bn1;

            // logits l[b,c] = sum_o u*v ; tile 2t: o=4q+reg, 2t+1: o=16+4q+reg
            float e0[4], e1[4], se0 = 0.f, se1 = 0.f;
#pragma unroll
            for (int t = 0; t < 4; ++t) {
                float lp0 = D0[2*t].x * v00[t].x + D0[2*t].y * v00[t].y +
                            D0[2*t].z * v00[t].z + D0[2*t].w * v00[t].w +
                            D0[2*t+1].x * v01[t].x + D0[2*t+1].y * v01[t].y +
                            D0[2*t+1].z * v01[t].z + D0[2*t+1].w * v01[t].w;
                float lp1 = D1[2*t].x * v10[t].x + D1[2*t].y * v10[t].y +
                            D1[2*t].z * v10[t].z + D1[2*t].w * v10[t].w +
                            D1[2*t+1].x * v11[t].x + D1[2*t+1].y * v11[t].y +
                            D1[2*t+1].z * v11[t].z + D1[2*t+1].w * v11[t].w;
                lp0 += __shfl_xor(lp0, 16, 64);   // sum over quads (o coverage)
                lp0 += __shfl_xor(lp0, 32, 64);
                lp1 += __shfl_xor(lp1, 16, 64);
                lp1 += __shfl_xor(lp1, 32, 64);
                e0[t] = __expf(lp0); se0 += e0[t]; // no max-subtract (|l| small)
                e1[t] = __expf(lp1); se1 += e1[t];
            }
            if (lane < 32) sums[rr & 1][q][bl][w] = (q == 0) ? se0 : se1;
            // lgkmcnt-only drain: LDS write visible, W loads stay in flight.
            asm volatile("s_waitcnt lgkmcnt(0)" ::: "memory");
            __builtin_amdgcn_s_barrier();
            asm volatile("" ::: "memory");
            const floatx4 sa0 = *(const floatx4*)(&sums[rr & 1][0][bl][0]);
            const floatx4 sa1 = *(const floatx4*)(&sums[rr & 1][0][bl][4]);
            const floatx4 sb0 = *(const floatx4*)(&sums[rr & 1][1][bl][0]);
            const floatx4 sb1 = *(const floatx4*)(&sums[rr & 1][1][bl][4]);
            const float tot0 = sa0.x + sa0.y + sa0.z + sa0.w +
                               sa1.x + sa1.y + sa1.z + sa1.w;
            const float tot1 = sb0.x + sb0.y + sb0.z + sb0.w +
                               sb1.x + sb1.y + sb1.z + sb1.w;
            const float winv0 = __builtin_amdgcn_rcpf(tot0);
            const float winv1 = __builtin_amdgcn_rcpf(tot1);
#pragma unroll
            for (int t = 0; t < 4; ++t) {
                const float wt0 = e0[t] * winv0;
                const float wt1 = e1[t] * winv1;
                accS0[2*t]   += wt0 * D0[2*t];
                accS0[2*t+1] += wt0 * D0[2*t+1];
                accS1[2*t]   += wt1 * D1[2*t];
                accS1[2*t+1] += wt1 * D1[2*t+1];
            }
        }
    }

    // store fp16 partials: co = w*128 + m*16 + 4q + reg (4 halves = 8B/store)
    const size_t sb = (((size_t)rc * 64 + b0 + bl)) * 1024 + w * 128 + 4 * q;
#pragma unroll
    for (int m = 0; m < 8; ++m) {
        const floatx4 a0 = accS0[m], a1 = accS1[m];
        const half4v h0 = {(_Float16)a0.x, (_Float16)a0.y, (_Float16)a0.z, (_Float16)a0.w};
        const half4v h1 = {(_Float16)a1.x, (_Float16)a1.y, (_Float16)a1.z, (_Float16)a1.w};
        *(half4v*)(s_part + sb + m * 16) = h0;
        *(half4v*)(s_part + sb + (size_t)16 * 1024 + m * 16) = h1;
    }
}

// Fused reduce(128 rc-partials fp16, fp32 accumulate) + squash.
// Grid: 64 b x 8 co-octs = 512 blocks; 256 thr = 8 k-groups x 32 half4.
__global__ __launch_bounds__(256)
void reduce_squash(const _Float16* __restrict__ sp, float scale,
                   float* __restrict__ vout, const float* __restrict__ vprev,
                   float* __restrict__ vsum) {
    const int b = blockIdx.x >> 3, oct = blockIdx.x & 7;
    const int t = threadIdx.x;
    const int kg = t >> 5, ci = t & 31;
    const size_t base = (size_t)b * 1024 + (size_t)oct * 128 + (size_t)ci * 4;

    floatx4 acc0 = (floatx4){0.f, 0.f, 0.f, 0.f};
    floatx4 acc1 = (floatx4){0.f, 0.f, 0.f, 0.f};
#pragma unroll
    for (int k = kg * 16; k < kg * 16 + 16; k += 2) {
        const half4v h0 = *(const half4v*)(sp + (size_t)k * 65536 + base);
        const half4v h1 = *(const half4v*)(sp + (size_t)(k + 1) * 65536 + base);
        acc0 += (floatx4){(float)h0.x, (float)h0.y, (float)h0.z, (float)h0.w};
        acc1 += (floatx4){(float)h1.x, (float)h1.y, (float)h1.z, (float)h1.w};
    }
    const floatx4 acc = acc0 + acc1;

    __shared__ __attribute__((aligned(16))) float red[8][128];
    *(floatx4*)(&red[kg][ci * 4]) = acc;
    __syncthreads();

    if (t < 128) {                     // element f = t : c = oct*4 + (t>>5), o = t&31
        float s = 0.f;
#pragma unroll
        for (int g = 0; g < 8; ++g) s += red[g][t];
        s *= scale;
        float n2 = s * s;              // norm over o: lane bits 0..4
        n2 += __shfl_xor(n2, 1, 64);
        n2 += __shfl_xor(n2, 2, 64);
        n2 += __shfl_xor(n2, 4, 64);
        n2 += __shfl_xor(n2, 8, 64);
        n2 += __shfl_xor(n2, 16, 64);
        const float norm = sqrtf(n2);
        const float f = (n2 / (1.f + n2)) / (norm + 1e-8f);
        const float vv = s * f;
        const size_t o = (size_t)b * 1024 + (size_t)oct * 128 + t;
        if (vout) vout[o] = vv;
        if (vsum) vsum[o] = vv + vprev[o];
    }
}

extern "C" void kernel_launch(void* const* d_in, const int* in_sizes, int n_in,
                              void* d_out, int out_size, void* d_ws, size_t ws_size,
                              hipStream_t stream) {
    const float* x = (const float*)d_in[0];   // [64,2048,16]
    const float* W = (const float*)d_in[1];   // [2048,32,32,16]
    float* out = (float*)d_out;               // [64,32,32]

    char* ws = (char*)d_ws;                   // ws >= 512 MB (harness fills 512MB)
    _Float16* Wh     = (_Float16*)ws;                               // 64 MB
    _Float16* s_part = (_Float16*)(ws + (size_t)67108864);          // 16 MB
    float* v1        = (float*)(ws + (size_t)67108864 + 33554432);             // 256 KB
    float* v12       = (float*)(ws + (size_t)67108864 + 33554432 + 262144);    // 256 KB

    const int ublocks = NG * NRC2;   // 256 = 1 block/CU

    // iter 1: reads W fp32, persists Wh fp16; 1/32 applied as squash pre-scale
    upass<0><<<ublocks, 512, 0, stream>>>(x, W, Wh, nullptr, s_part);
    reduce_squash<<<512, 256, 0, stream>>>(s_part, 1.f / 32.f, v1, nullptr, nullptr);

    // iter 2: logits = u.v1 ; keep only v12 = v1 + v2
    upass<1><<<ublocks, 512, 0, stream>>>(x, nullptr, Wh, v1, s_part);
    reduce_squash<<<512, 256, 0, stream>>>(s_part, 1.f, nullptr, v1, v12);

    // iter 3: logits = u.(v1+v2) ; output v3
    upass<2><<<ublocks, 512, 0, stream>>>(x, nullptr, Wh, v12, s_part);
    reduce_squash<<<512, 256, 0, stream>>>(s_part, 1.f, out, nullptr, nullptr);
}